// Round 1
// baseline (559.988 us; speedup 1.0000x reference)
//
#include <hip/hip_runtime.h>
#include <hip/hip_bf16.h>

#define N_NODES 50000
#define N_EDGES 800000
#define IN_C 512
#define HID_C 256
#define OUT_C 2
#define TOT_E (N_EDGES + N_NODES)   // edges + self loops

// ---------------- init / degree ----------------

__global__ void init_counts_kernel(int* counts, int n) {
    int i = blockIdx.x * blockDim.x + threadIdx.x;
    if (i < n) counts[i] = 1;   // self loop
}

__global__ void count_kernel(const int* __restrict__ dst, int* counts, int e) {
    int i = blockIdx.x * blockDim.x + threadIdx.x;
    if (i < e) atomicAdd(&counts[dst[i]], 1);
}

__global__ void dinv_kernel(const int* __restrict__ counts, float* dinv, int n) {
    int i = blockIdx.x * blockDim.x + threadIdx.x;
    if (i < n) dinv[i] = rsqrtf((float)counts[i]);
}

// ---------------- exclusive scan (single block, 1024 thr) ----------------

__global__ __launch_bounds__(1024) void scan_kernel(const int* __restrict__ counts,
                                                    int* offs, int n) {
    __shared__ int buf[1024];
    __shared__ int carry_s;
    if (threadIdx.x == 0) carry_s = 0;
    __syncthreads();
    for (int base = 0; base < n; base += 1024) {
        int c = carry_s;
        int i = base + threadIdx.x;
        int v = (i < n) ? counts[i] : 0;
        buf[threadIdx.x] = v;
        __syncthreads();
        #pragma unroll
        for (int off = 1; off < 1024; off <<= 1) {
            int t = (threadIdx.x >= off) ? buf[threadIdx.x - off] : 0;
            __syncthreads();
            buf[threadIdx.x] += t;
            __syncthreads();
        }
        if (i < n) offs[i + 1] = c + buf[threadIdx.x];
        __syncthreads();
        if (threadIdx.x == 0) carry_s = c + buf[1023];
        __syncthreads();
    }
    if (threadIdx.x == 0) offs[0] = 0;
}

__global__ void cursor_kernel(const int* __restrict__ offs, int* cursor, int n) {
    int i = blockIdx.x * blockDim.x + threadIdx.x;
    if (i < n) cursor[i] = offs[i];
}

// ---------------- CSR fill (edges + self loops) ----------------

__global__ void fill_kernel(const int* __restrict__ src, const int* __restrict__ dst,
                            const float* __restrict__ dinv, int* cursor,
                            int* csr_src, float* csr_norm, int e, int n) {
    int i = blockIdx.x * blockDim.x + threadIdx.x;
    int total = e + n;
    if (i >= total) return;
    int s, d;
    if (i < e) { s = src[i]; d = dst[i]; }
    else       { s = d = i - e; }
    int p = atomicAdd(&cursor[d], 1);
    csr_src[p]  = s;
    csr_norm[p] = dinv[s] * dinv[d];
}

// ---------------- GEMM: h = x @ W1  (f32, 64x64x16 tile, 4x4/thread) ----------------

__global__ __launch_bounds__(256) void gemm1_kernel(const float* __restrict__ A, // [M,K]
                                                    const float* __restrict__ B, // [K,N]
                                                    float* __restrict__ C,       // [M,N]
                                                    int M, int K, int N) {
    __shared__ float As[16][68];
    __shared__ float Bs[16][68];
    const int bm = blockIdx.x * 64;
    const int bn = blockIdx.y * 64;
    const int tid = threadIdx.x;
    const int tx = tid & 15, ty = tid >> 4;
    float acc[4][4] = {};
    for (int k0 = 0; k0 < K; k0 += 16) {
        {   // A tile 64x16, one float4 per thread, transpose into As[k][m]
            int a_row = tid >> 2;
            int a_col = (tid & 3) * 4;
            int gr = bm + a_row; if (gr >= M) gr = M - 1;
            const float4 v = *reinterpret_cast<const float4*>(&A[(size_t)gr * K + k0 + a_col]);
            As[a_col + 0][a_row] = v.x;
            As[a_col + 1][a_row] = v.y;
            As[a_col + 2][a_row] = v.z;
            As[a_col + 3][a_row] = v.w;
        }
        {   // B tile 16x64, one float4 per thread
            int b_row = tid >> 4;
            int b_col = (tid & 15) * 4;
            const float4 v = *reinterpret_cast<const float4*>(&B[(size_t)(k0 + b_row) * N + bn + b_col]);
            *reinterpret_cast<float4*>(&Bs[b_row][b_col]) = v;
        }
        __syncthreads();
        #pragma unroll
        for (int k = 0; k < 16; ++k) {
            float a[4], b[4];
            #pragma unroll
            for (int i = 0; i < 4; ++i) a[i] = As[k][ty * 4 + i];
            #pragma unroll
            for (int j = 0; j < 4; ++j) b[j] = Bs[k][tx * 4 + j];
            #pragma unroll
            for (int i = 0; i < 4; ++i)
                #pragma unroll
                for (int j = 0; j < 4; ++j)
                    acc[i][j] += a[i] * b[j];
        }
        __syncthreads();
    }
    #pragma unroll
    for (int i = 0; i < 4; ++i) {
        int r = bm + ty * 4 + i;
        if (r < M) {
            #pragma unroll
            for (int j = 0; j < 4; ++j)
                C[(size_t)r * N + bn + tx * 4 + j] = acc[i][j];
        }
    }
}

// ---------------- fused aggregation-1 + bias + ReLU + @W2 ----------------
// one block per node, thread = feature (256)

__global__ __launch_bounds__(256) void agg1_kernel(const float* __restrict__ h,   // [N,256]
                                                   const int* __restrict__ offs,
                                                   const int* __restrict__ csr_src,
                                                   const float* __restrict__ csr_norm,
                                                   const float* __restrict__ b1,  // [256]
                                                   const float* __restrict__ W2,  // [256,2]
                                                   float* __restrict__ h2) {      // [N,2]
    const int n = blockIdx.x;
    const int f = threadIdx.x;
    const int s = offs[n], e = offs[n + 1];
    float acc = 0.f;
    for (int i = s; i < e; ++i) {
        int sc = csr_src[i];
        float w = csr_norm[i];
        acc += h[(size_t)sc * HID_C + f] * w;
    }
    float v = acc + b1[f];
    v = v > 0.f ? v : 0.f;
    float c0 = v * W2[f * 2 + 0];
    float c1 = v * W2[f * 2 + 1];
    #pragma unroll
    for (int o = 32; o > 0; o >>= 1) {
        c0 += __shfl_down(c0, o, 64);
        c1 += __shfl_down(c1, o, 64);
    }
    __shared__ float red[4][2];
    int wid = threadIdx.x >> 6, lane = threadIdx.x & 63;
    if (lane == 0) { red[wid][0] = c0; red[wid][1] = c1; }
    __syncthreads();
    if (threadIdx.x == 0) {
        h2[n * 2 + 0] = red[0][0] + red[1][0] + red[2][0] + red[3][0];
        h2[n * 2 + 1] = red[0][1] + red[1][1] + red[2][1] + red[3][1];
    }
}

// ---------------- aggregation-2 (+b2) : thread per node ----------------

__global__ void agg2_kernel(const float* __restrict__ h2,  // [N,2]
                            const int* __restrict__ offs,
                            const int* __restrict__ csr_src,
                            const float* __restrict__ csr_norm,
                            const float* __restrict__ b2,
                            float* __restrict__ out, int n_nodes) {
    int n = blockIdx.x * blockDim.x + threadIdx.x;
    if (n >= n_nodes) return;
    int s = offs[n], e = offs[n + 1];
    float a0 = b2[0], a1 = b2[1];
    for (int i = s; i < e; ++i) {
        int sc = csr_src[i];
        float w = csr_norm[i];
        a0 += h2[sc * 2 + 0] * w;
        a1 += h2[sc * 2 + 1] * w;
    }
    out[n * 2 + 0] = a0;
    out[n * 2 + 1] = a1;
}

// ---------------- host ----------------

static inline size_t align_up(size_t x) { return (x + 255) & ~(size_t)255; }

extern "C" void kernel_launch(void* const* d_in, const int* in_sizes, int n_in,
                              void* d_out, int out_size, void* d_ws, size_t ws_size,
                              hipStream_t stream) {
    const float* x   = (const float*)d_in[0];
    const int*   ei  = (const int*)d_in[1];     // [2, E] int32
    const float* W1  = (const float*)d_in[2];
    const float* b1  = (const float*)d_in[3];
    const float* W2  = (const float*)d_in[4];
    const float* b2  = (const float*)d_in[5];
    float* out = (float*)d_out;

    const int* e_src = ei;
    const int* e_dst = ei + N_EDGES;

    char* ws = (char*)d_ws;
    int*   counts   = (int*)ws;                 ws += align_up((size_t)N_NODES * 4);
    int*   offs     = (int*)ws;                 ws += align_up((size_t)(N_NODES + 1) * 4);
    int*   cursor   = (int*)ws;                 ws += align_up((size_t)N_NODES * 4);
    int*   csr_src  = (int*)ws;                 ws += align_up((size_t)TOT_E * 4);
    float* csr_norm = (float*)ws;               ws += align_up((size_t)TOT_E * 4);
    float* dinv     = (float*)ws;               ws += align_up((size_t)N_NODES * 4);
    float* h        = (float*)ws;               ws += align_up((size_t)N_NODES * HID_C * 4);
    float* h2       = (float*)ws;               ws += align_up((size_t)N_NODES * 2 * 4);

    const int nb_n = (N_NODES + 255) / 256;
    const int nb_e = (N_EDGES + 255) / 256;
    const int nb_t = (TOT_E + 255) / 256;

    init_counts_kernel<<<nb_n, 256, 0, stream>>>(counts, N_NODES);
    count_kernel<<<nb_e, 256, 0, stream>>>(e_dst, counts, N_EDGES);
    dinv_kernel<<<nb_n, 256, 0, stream>>>(counts, dinv, N_NODES);
    scan_kernel<<<1, 1024, 0, stream>>>(counts, offs, N_NODES);
    cursor_kernel<<<nb_n, 256, 0, stream>>>(offs, cursor, N_NODES);
    fill_kernel<<<nb_t, 256, 0, stream>>>(e_src, e_dst, dinv, cursor,
                                          csr_src, csr_norm, N_EDGES, N_NODES);

    dim3 ggrid((N_NODES + 63) / 64, HID_C / 64);
    gemm1_kernel<<<ggrid, 256, 0, stream>>>(x, W1, h, N_NODES, IN_C, HID_C);

    agg1_kernel<<<N_NODES, 256, 0, stream>>>(h, offs, csr_src, csr_norm, b1, W2, h2);
    agg2_kernel<<<nb_n, 256, 0, stream>>>(h2, offs, csr_src, csr_norm, b2, out, N_NODES);
}

// Round 2
// 324.008 us; speedup vs baseline: 1.7283x; 1.7283x over previous
//
#include <hip/hip_runtime.h>
#include <hip/hip_bf16.h>
#include <stdint.h>

#define N_NODES 50000
#define N_EDGES 800000
#define IN_C 512
#define HID_C 256
#define TOT_E (N_EDGES + N_NODES)   // edges + self loops

typedef __attribute__((ext_vector_type(8))) short bf16x8;
typedef __attribute__((ext_vector_type(4))) float f32x4;
typedef __attribute__((address_space(3))) uint32_t lds_u32_t;
typedef __attribute__((address_space(1))) const uint32_t g_u32_t;

__device__ __forceinline__ void g2l16(const void* g, void* l) {
    __builtin_amdgcn_global_load_lds((g_u32_t*)g, (lds_u32_t*)l, 16, 0, 0);
}

__device__ __forceinline__ unsigned short f2bf(float f) {
    uint32_t u = __float_as_uint(f);
    uint32_t r = (u + 0x7fff + ((u >> 16) & 1)) >> 16;
    return (unsigned short)r;
}

__device__ __forceinline__ float bf2f(unsigned short b) {
    return __uint_as_float(((uint32_t)b) << 16);
}

// ---------------- degree / CSR build ----------------

__global__ void init_counts_kernel(int* counts, int n) {
    int i = blockIdx.x * blockDim.x + threadIdx.x;
    if (i < n) counts[i] = 1;   // self loop
}

__global__ void count_kernel(const int* __restrict__ dst, int* counts, int e) {
    int i = blockIdx.x * blockDim.x + threadIdx.x;
    if (i < e) atomicAdd(&counts[dst[i]], 1);
}

__global__ void dinv_kernel(const int* __restrict__ counts, float* dinv, int n) {
    int i = blockIdx.x * blockDim.x + threadIdx.x;
    if (i < n) dinv[i] = rsqrtf((float)counts[i]);
}

// hierarchical scan: 196 blocks x 256
__global__ __launch_bounds__(256) void scan1_kernel(const int* __restrict__ counts,
                                                    int* __restrict__ incl,
                                                    int* __restrict__ bsum, int n) {
    __shared__ int buf[256];
    const int i = blockIdx.x * 256 + threadIdx.x;
    const int v = (i < n) ? counts[i] : 0;
    buf[threadIdx.x] = v;
    __syncthreads();
    #pragma unroll
    for (int off = 1; off < 256; off <<= 1) {
        const int t2 = (threadIdx.x >= off) ? buf[threadIdx.x - off] : 0;
        __syncthreads();
        buf[threadIdx.x] += t2;
        __syncthreads();
    }
    if (i < n) incl[i] = buf[threadIdx.x];
    if (threadIdx.x == 255) bsum[blockIdx.x] = buf[255];
}

__global__ __launch_bounds__(256) void scan2_kernel(const int* __restrict__ bsum,
                                                    int* __restrict__ bpre, int nb) {
    __shared__ int buf[256];
    const int v = (threadIdx.x < nb) ? bsum[threadIdx.x] : 0;
    buf[threadIdx.x] = v;
    __syncthreads();
    #pragma unroll
    for (int off = 1; off < 256; off <<= 1) {
        const int t2 = (threadIdx.x >= off) ? buf[threadIdx.x - off] : 0;
        __syncthreads();
        buf[threadIdx.x] += t2;
        __syncthreads();
    }
    if (threadIdx.x < nb) bpre[threadIdx.x] = buf[threadIdx.x] - v;  // exclusive
}

__global__ void scan3_kernel(const int* __restrict__ incl, const int* __restrict__ counts,
                             const int* __restrict__ bpre, int* __restrict__ offs,
                             int* __restrict__ cursor, int n) {
    const int i = blockIdx.x * 256 + threadIdx.x;
    if (i >= n) return;
    const int e = incl[i] + bpre[blockIdx.x];
    offs[i + 1] = e;
    cursor[i] = e - counts[i];
    if (i == 0) offs[0] = 0;
}

__global__ void fill_kernel(const int* __restrict__ src, const int* __restrict__ dst,
                            const float* __restrict__ dinv, int* cursor,
                            int* csr_src, float* csr_norm, int e, int n) {
    int i = blockIdx.x * blockDim.x + threadIdx.x;
    int total = e + n;
    if (i >= total) return;
    int s, d;
    if (i < e) { s = src[i]; d = dst[i]; }
    else       { s = d = i - e; }
    int p = atomicAdd(&cursor[d], 1);
    csr_src[p]  = s;
    csr_norm[p] = dinv[s] * dinv[d];
}

// ---------------- W1 transpose+convert: Wt[n][k] = bf16(W1[k][n]) ----------------

__global__ void transw_kernel(const float* __restrict__ W, unsigned short* __restrict__ Wt) {
    const int n = blockIdx.x;  // 256
    for (int k = threadIdx.x; k < IN_C; k += blockDim.x)
        Wt[n * IN_C + k] = f2bf(W[k * HID_C + n]);
}

// ---------------- GEMM: h = bf16(x) @ W1, bf16 MFMA, tile 64x256x64 ----------------
// A: f32 [M,512] converted inline; B: Wt [256,512] bf16 (W1^T) via global_load_lds.
// LDS tiles stored [row][64] bf16 with 16B-slot XOR swizzle: slot = c ^ (row&7).

__global__ __launch_bounds__(256) void gemm_kernel(
    const float* __restrict__ A,          // [M, 512] f32
    const unsigned short* __restrict__ Bt,// [256, 512] bf16
    unsigned short* __restrict__ hB,      // [M, 256] bf16 out
    int M)
{
    __shared__ unsigned short As[2][64 * 64];    // 8 KB each
    __shared__ unsigned short Bs[2][256 * 64];   // 32 KB each
    const int t = threadIdx.x;
    const int bm = blockIdx.x * 64;
    const int w = t >> 6, l = t & 63;
    const int wr = (w >> 1) * 32;      // 0 / 32
    const int wc = (w & 1) * 128;      // 0 / 128
    const int l15 = l & 15, l4 = l >> 4;

    f32x4 acc[2][8] = {};
    float4 av[4];

    auto stageB = [&](int buf, int kt) {
        #pragma unroll
        for (int q = 0; q < 8; ++q) {
            const int r  = q * 32 + (t >> 3);           // B col 0..255
            const int ck = (t & 7) ^ (r & 7);           // pre-swizzled source slot
            g2l16(&Bt[(size_t)r * IN_C + kt * 64 + ck * 8],
                  &Bs[buf][(q * 256 + t) * 8]);
        }
    };
    auto loadA = [&](int kt) {
        const int r = t >> 2;
        int gr = bm + r; if (gr >= M) gr = M - 1;
        const float* p = &A[(size_t)gr * IN_C + kt * 64 + (t & 3) * 16];
        #pragma unroll
        for (int j = 0; j < 4; ++j) av[j] = ((const float4*)p)[j];
    };
    auto writeA = [&](int buf) {
        const int r = t >> 2;
        unsigned short tmp[16];
        #pragma unroll
        for (int j = 0; j < 4; ++j) {
            tmp[4*j+0] = f2bf(av[j].x); tmp[4*j+1] = f2bf(av[j].y);
            tmp[4*j+2] = f2bf(av[j].z); tmp[4*j+3] = f2bf(av[j].w);
        }
        const int c0 = (t & 3) * 2;
        #pragma unroll
        for (int hh = 0; hh < 2; ++hh) {
            const int ck = (c0 + hh) ^ (r & 7);
            *(uint4*)&As[buf][r * 64 + ck * 8] = *(const uint4*)&tmp[hh * 8];
        }
    };
    auto compute = [&](int buf) {
        #pragma unroll
        for (int kc = 0; kc < 2; ++kc) {
            bf16x8 a[2], b[8];
            #pragma unroll
            for (int mi = 0; mi < 2; ++mi) {
                const int r  = wr + mi * 16 + l15;
                const int ck = (kc * 4 + l4) ^ (r & 7);
                a[mi] = *(const bf16x8*)&As[buf][r * 64 + ck * 8];
            }
            #pragma unroll
            for (int nj = 0; nj < 8; ++nj) {
                const int cn = wc + nj * 16 + l15;
                const int ck = (kc * 4 + l4) ^ (cn & 7);
                b[nj] = *(const bf16x8*)&Bs[buf][cn * 64 + ck * 8];
            }
            #pragma unroll
            for (int mi = 0; mi < 2; ++mi)
                #pragma unroll
                for (int nj = 0; nj < 8; ++nj)
                    acc[mi][nj] = __builtin_amdgcn_mfma_f32_16x16x32_bf16(
                        a[mi], b[nj], acc[mi][nj], 0, 0, 0);
        }
    };

    loadA(0); stageB(0, 0); writeA(0);
    __syncthreads();
    for (int kt = 0; kt < 8; ++kt) {
        const int cur = kt & 1;
        if (kt < 7) { stageB(cur ^ 1, kt + 1); loadA(kt + 1); }  // issue early
        compute(cur);
        if (kt < 7) writeA(cur ^ 1);                             // write late
        __syncthreads();
    }

    #pragma unroll
    for (int mi = 0; mi < 2; ++mi)
        #pragma unroll
        for (int nj = 0; nj < 8; ++nj)
            #pragma unroll
            for (int rr = 0; rr < 4; ++rr) {
                const int m = bm + wr + mi * 16 + l4 * 4 + rr;
                const int n = wc + nj * 16 + l15;
                if (m < M) hB[(size_t)m * HID_C + n] = f2bf(acc[mi][nj][rr]);
            }
}

// ---------------- fused aggregation-1 + bias + ReLU + @W2 ----------------

__global__ __launch_bounds__(256) void agg1_kernel(const unsigned short* __restrict__ h, // [N,256] bf16
                                                   const int* __restrict__ offs,
                                                   const int* __restrict__ csr_src,
                                                   const float* __restrict__ csr_norm,
                                                   const float* __restrict__ b1,
                                                   const float* __restrict__ W2,  // [256,2]
                                                   float* __restrict__ h2) {      // [N,2]
    const int n = blockIdx.x;
    const int f = threadIdx.x;
    const int s = offs[n], e = offs[n + 1];
    float acc = 0.f;
    for (int i = s; i < e; ++i) {
        const int sc = csr_src[i];
        const float w = csr_norm[i];
        acc += bf2f(h[(size_t)sc * HID_C + f]) * w;
    }
    float v = acc + b1[f];
    v = v > 0.f ? v : 0.f;
    float c0 = v * W2[f * 2 + 0];
    float c1 = v * W2[f * 2 + 1];
    #pragma unroll
    for (int o = 32; o > 0; o >>= 1) {
        c0 += __shfl_down(c0, o, 64);
        c1 += __shfl_down(c1, o, 64);
    }
    __shared__ float red[4][2];
    const int wid = threadIdx.x >> 6, lane = threadIdx.x & 63;
    if (lane == 0) { red[wid][0] = c0; red[wid][1] = c1; }
    __syncthreads();
    if (threadIdx.x == 0) {
        h2[n * 2 + 0] = red[0][0] + red[1][0] + red[2][0] + red[3][0];
        h2[n * 2 + 1] = red[0][1] + red[1][1] + red[2][1] + red[3][1];
    }
}

// ---------------- aggregation-2 (+b2) ----------------

__global__ void agg2_kernel(const float* __restrict__ h2,
                            const int* __restrict__ offs,
                            const int* __restrict__ csr_src,
                            const float* __restrict__ csr_norm,
                            const float* __restrict__ b2,
                            float* __restrict__ out, int n_nodes) {
    int n = blockIdx.x * blockDim.x + threadIdx.x;
    if (n >= n_nodes) return;
    int s = offs[n], e = offs[n + 1];
    float a0 = b2[0], a1 = b2[1];
    for (int i = s; i < e; ++i) {
        int sc = csr_src[i];
        float w = csr_norm[i];
        a0 += h2[sc * 2 + 0] * w;
        a1 += h2[sc * 2 + 1] * w;
    }
    out[n * 2 + 0] = a0;
    out[n * 2 + 1] = a1;
}

// ---------------- host ----------------

static inline size_t align_up(size_t x) { return (x + 255) & ~(size_t)255; }

extern "C" void kernel_launch(void* const* d_in, const int* in_sizes, int n_in,
                              void* d_out, int out_size, void* d_ws, size_t ws_size,
                              hipStream_t stream) {
    const float* x   = (const float*)d_in[0];
    const int*   ei  = (const int*)d_in[1];
    const float* W1  = (const float*)d_in[2];
    const float* b1  = (const float*)d_in[3];
    const float* W2  = (const float*)d_in[4];
    const float* b2  = (const float*)d_in[5];
    float* out = (float*)d_out;

    const int* e_src = ei;
    const int* e_dst = ei + N_EDGES;

    char* ws = (char*)d_ws;
    int*   counts   = (int*)ws;             ws += align_up((size_t)N_NODES * 4);
    int*   incl     = (int*)ws;             ws += align_up((size_t)N_NODES * 4);
    int*   bsum     = (int*)ws;             ws += align_up(256 * 4);
    int*   bpre     = (int*)ws;             ws += align_up(256 * 4);
    int*   offs     = (int*)ws;             ws += align_up((size_t)(N_NODES + 1) * 4);
    int*   cursor   = (int*)ws;             ws += align_up((size_t)N_NODES * 4);
    float* dinv     = (float*)ws;           ws += align_up((size_t)N_NODES * 4);
    int*   csr_src  = (int*)ws;             ws += align_up((size_t)TOT_E * 4);
    float* csr_norm = (float*)ws;           ws += align_up((size_t)TOT_E * 4);
    unsigned short* Wt = (unsigned short*)ws; ws += align_up((size_t)HID_C * IN_C * 2);
    unsigned short* h  = (unsigned short*)ws; ws += align_up((size_t)N_NODES * HID_C * 2);
    float* h2       = (float*)ws;           ws += align_up((size_t)N_NODES * 2 * 4);

    const int nb_n = (N_NODES + 255) / 256;   // 196
    const int nb_e = (N_EDGES + 255) / 256;
    const int nb_t = (TOT_E + 255) / 256;

    init_counts_kernel<<<nb_n, 256, 0, stream>>>(counts, N_NODES);
    count_kernel<<<nb_e, 256, 0, stream>>>(e_dst, counts, N_EDGES);
    dinv_kernel<<<nb_n, 256, 0, stream>>>(counts, dinv, N_NODES);
    scan1_kernel<<<nb_n, 256, 0, stream>>>(counts, incl, bsum, N_NODES);
    scan2_kernel<<<1, 256, 0, stream>>>(bsum, bpre, nb_n);
    scan3_kernel<<<nb_n, 256, 0, stream>>>(incl, counts, bpre, offs, cursor, N_NODES);
    transw_kernel<<<HID_C, 256, 0, stream>>>(W1, Wt);
    fill_kernel<<<nb_t, 256, 0, stream>>>(e_src, e_dst, dinv, cursor,
                                          csr_src, csr_norm, N_EDGES, N_NODES);

    gemm_kernel<<<(N_NODES + 63) / 64, 256, 0, stream>>>(x, Wt, h, N_NODES);

    agg1_kernel<<<N_NODES, 256, 0, stream>>>(h, offs, csr_src, csr_norm, b1, W2, h2);
    agg2_kernel<<<nb_n, 256, 0, stream>>>(h2, offs, csr_src, csr_norm, b2, out, N_NODES);
}

// Round 3
// 199.873 us; speedup vs baseline: 2.8017x; 1.6211x over previous
//
#include <hip/hip_runtime.h>
#include <hip/hip_bf16.h>
#include <stdint.h>

#define N_NODES 50000
#define N_EDGES 800000
#define IN_C 512
#define HID_C 256
#define TOT_E (N_EDGES + N_NODES)   // edges + self loops

typedef __attribute__((ext_vector_type(8))) short bf16x8;
typedef __attribute__((ext_vector_type(4))) float f32x4;
typedef __attribute__((address_space(3))) uint32_t lds_u32_t;
typedef __attribute__((address_space(1))) const uint32_t g_u32_t;

__device__ __forceinline__ void g2l16(const void* g, void* l) {
    __builtin_amdgcn_global_load_lds((g_u32_t*)g, (lds_u32_t*)l, 16, 0, 0);
}

__device__ __forceinline__ unsigned short f2bf(float f) {
    uint32_t u = __float_as_uint(f);
    uint32_t r = (u + 0x7fff + ((u >> 16) & 1)) >> 16;
    return (unsigned short)r;
}

__device__ __forceinline__ float bf2f(unsigned short b) {
    return __uint_as_float(((uint32_t)b) << 16);
}

// ---------------- degree / CSR build ----------------

__global__ void init_counts_kernel(int* counts, int n) {
    int i = blockIdx.x * blockDim.x + threadIdx.x;
    if (i < n) counts[i] = 1;   // self loop
}

__global__ void count_kernel(const int* __restrict__ dst, int* counts, int e) {
    int i = blockIdx.x * blockDim.x + threadIdx.x;
    if (i < e) atomicAdd(&counts[dst[i]], 1);
}

__global__ void dinv_kernel(const int* __restrict__ counts, float* dinv, int n) {
    int i = blockIdx.x * blockDim.x + threadIdx.x;
    if (i < n) dinv[i] = rsqrtf((float)counts[i]);
}

// hierarchical scan: 196 blocks x 256
__global__ __launch_bounds__(256) void scan1_kernel(const int* __restrict__ counts,
                                                    int* __restrict__ incl,
                                                    int* __restrict__ bsum, int n) {
    __shared__ int buf[256];
    const int i = blockIdx.x * 256 + threadIdx.x;
    const int v = (i < n) ? counts[i] : 0;
    buf[threadIdx.x] = v;
    __syncthreads();
    #pragma unroll
    for (int off = 1; off < 256; off <<= 1) {
        const int t2 = (threadIdx.x >= off) ? buf[threadIdx.x - off] : 0;
        __syncthreads();
        buf[threadIdx.x] += t2;
        __syncthreads();
    }
    if (i < n) incl[i] = buf[threadIdx.x];
    if (threadIdx.x == 255) bsum[blockIdx.x] = buf[255];
}

__global__ __launch_bounds__(256) void scan2_kernel(const int* __restrict__ bsum,
                                                    int* __restrict__ bpre, int nb) {
    __shared__ int buf[256];
    const int v = (threadIdx.x < nb) ? bsum[threadIdx.x] : 0;
    buf[threadIdx.x] = v;
    __syncthreads();
    #pragma unroll
    for (int off = 1; off < 256; off <<= 1) {
        const int t2 = (threadIdx.x >= off) ? buf[threadIdx.x - off] : 0;
        __syncthreads();
        buf[threadIdx.x] += t2;
        __syncthreads();
    }
    if (threadIdx.x < nb) bpre[threadIdx.x] = buf[threadIdx.x] - v;  // exclusive
}

__global__ void scan3_kernel(const int* __restrict__ incl, const int* __restrict__ counts,
                             const int* __restrict__ bpre, int* __restrict__ offs,
                             int* __restrict__ cursor, int n) {
    const int i = blockIdx.x * 256 + threadIdx.x;
    if (i >= n) return;
    const int e = incl[i] + bpre[blockIdx.x];
    offs[i + 1] = e;
    cursor[i] = e - counts[i];
    if (i == 0) offs[0] = 0;
}

__global__ void fill_kernel(const int* __restrict__ src, const int* __restrict__ dst,
                            const float* __restrict__ dinv, int* cursor,
                            int* csr_src, float* csr_norm, int e, int n) {
    int i = blockIdx.x * blockDim.x + threadIdx.x;
    int total = e + n;
    if (i >= total) return;
    int s, d;
    if (i < e) { s = src[i]; d = dst[i]; }
    else       { s = d = i - e; }
    int p = atomicAdd(&cursor[d], 1);
    csr_src[p]  = s;
    csr_norm[p] = dinv[s] * dinv[d];
}

// ---------------- W1 transpose+convert: Wt[n][k] = bf16(W1[k][n]) ----------------

__global__ void transw_kernel(const float* __restrict__ W, unsigned short* __restrict__ Wt) {
    const int n = blockIdx.x;  // 256
    for (int k = threadIdx.x; k < IN_C; k += blockDim.x)
        Wt[n * IN_C + k] = f2bf(W[k * HID_C + n]);
}

// ---------------- GEMM: h = bf16(x) @ W1, bf16 MFMA, tile 64x256x64 ----------------

__global__ __launch_bounds__(256) void gemm_kernel(
    const float* __restrict__ A,          // [M, 512] f32
    const unsigned short* __restrict__ Bt,// [256, 512] bf16
    unsigned short* __restrict__ hB,      // [M, 256] bf16 out
    int M)
{
    __shared__ unsigned short As[2][64 * 64];    // 8 KB each
    __shared__ unsigned short Bs[2][256 * 64];   // 32 KB each
    const int t = threadIdx.x;
    const int bm = blockIdx.x * 64;
    const int w = t >> 6, l = t & 63;
    const int wr = (w >> 1) * 32;      // 0 / 32
    const int wc = (w & 1) * 128;      // 0 / 128
    const int l15 = l & 15, l4 = l >> 4;

    f32x4 acc[2][8] = {};
    float4 av[4];

    auto stageB = [&](int buf, int kt) {
        #pragma unroll
        for (int q = 0; q < 8; ++q) {
            const int r  = q * 32 + (t >> 3);           // B col 0..255
            const int ck = (t & 7) ^ (r & 7);           // pre-swizzled source slot
            g2l16(&Bt[(size_t)r * IN_C + kt * 64 + ck * 8],
                  &Bs[buf][(q * 256 + t) * 8]);
        }
    };
    auto loadA = [&](int kt) {
        const int r = t >> 2;
        int gr = bm + r; if (gr >= M) gr = M - 1;
        const float* p = &A[(size_t)gr * IN_C + kt * 64 + (t & 3) * 16];
        #pragma unroll
        for (int j = 0; j < 4; ++j) av[j] = ((const float4*)p)[j];
    };
    auto writeA = [&](int buf) {
        const int r = t >> 2;
        unsigned short tmp[16];
        #pragma unroll
        for (int j = 0; j < 4; ++j) {
            tmp[4*j+0] = f2bf(av[j].x); tmp[4*j+1] = f2bf(av[j].y);
            tmp[4*j+2] = f2bf(av[j].z); tmp[4*j+3] = f2bf(av[j].w);
        }
        const int c0 = (t & 3) * 2;
        #pragma unroll
        for (int hh = 0; hh < 2; ++hh) {
            const int ck = (c0 + hh) ^ (r & 7);
            *(uint4*)&As[buf][r * 64 + ck * 8] = *(const uint4*)&tmp[hh * 8];
        }
    };
    auto compute = [&](int buf) {
        #pragma unroll
        for (int kc = 0; kc < 2; ++kc) {
            bf16x8 a[2], b[8];
            #pragma unroll
            for (int mi = 0; mi < 2; ++mi) {
                const int r  = wr + mi * 16 + l15;
                const int ck = (kc * 4 + l4) ^ (r & 7);
                a[mi] = *(const bf16x8*)&As[buf][r * 64 + ck * 8];
            }
            #pragma unroll
            for (int nj = 0; nj < 8; ++nj) {
                const int cn = wc + nj * 16 + l15;
                const int ck = (kc * 4 + l4) ^ (cn & 7);
                b[nj] = *(const bf16x8*)&Bs[buf][cn * 64 + ck * 8];
            }
            #pragma unroll
            for (int mi = 0; mi < 2; ++mi)
                #pragma unroll
                for (int nj = 0; nj < 8; ++nj)
                    acc[mi][nj] = __builtin_amdgcn_mfma_f32_16x16x32_bf16(
                        a[mi], b[nj], acc[mi][nj], 0, 0, 0);
        }
    };

    loadA(0); stageB(0, 0); writeA(0);
    __syncthreads();
    for (int kt = 0; kt < 8; ++kt) {
        const int cur = kt & 1;
        if (kt < 7) { stageB(cur ^ 1, kt + 1); loadA(kt + 1); }  // issue early
        compute(cur);
        if (kt < 7) writeA(cur ^ 1);                             // write late
        __syncthreads();
    }

    #pragma unroll
    for (int mi = 0; mi < 2; ++mi)
        #pragma unroll
        for (int nj = 0; nj < 8; ++nj)
            #pragma unroll
            for (int rr = 0; rr < 4; ++rr) {
                const int m = bm + wr + mi * 16 + l4 * 4 + rr;
                const int n = wc + nj * 16 + l15;
                if (m < M) hB[(size_t)m * HID_C + n] = f2bf(acc[mi][nj][rr]);
            }
}

// ---------------- fused aggregation-1 + bias + ReLU + @W2 ----------------
// wave per node: 64 lanes x 4 feats (uint2 = 4 bf16 / neighbor row),
// lane-preloaded csr indices broadcast via shfl, 4-way unrolled gather ILP.

__device__ __forceinline__ void fma4(float* acc, uint2 r, float w) {
    acc[0] += __uint_as_float((r.x & 0xffffu) << 16) * w;
    acc[1] += __uint_as_float(r.x & 0xffff0000u) * w;
    acc[2] += __uint_as_float((r.y & 0xffffu) << 16) * w;
    acc[3] += __uint_as_float(r.y & 0xffff0000u) * w;
}

__global__ __launch_bounds__(256) void agg1_kernel(const unsigned short* __restrict__ h, // [N,256] bf16
                                                   const int* __restrict__ offs,
                                                   const int* __restrict__ csr_src,
                                                   const float* __restrict__ csr_norm,
                                                   const float* __restrict__ b1,
                                                   const float* __restrict__ W2,  // [256,2]
                                                   float* __restrict__ h2) {      // [N,2]
    const int node = blockIdx.x * 4 + (threadIdx.x >> 6);
    const int lane = threadIdx.x & 63;
    const int s = offs[node], e = offs[node + 1];
    const int f0 = lane << 2;

    float acc[4] = {0.f, 0.f, 0.f, 0.f};

    for (int base = s; base < e; base += 64) {
        const int rem = e - base;
        const int cnt = rem < 64 ? rem : 64;
        int idx = 0; float nw = 0.f;
        if (lane < cnt) { idx = csr_src[base + lane]; nw = csr_norm[base + lane]; }
        int i = 0;
        for (; i + 4 <= cnt; i += 4) {
            const int   i0 = __shfl(idx, i,     64); const float w0 = __shfl(nw, i,     64);
            const int   i1 = __shfl(idx, i + 1, 64); const float w1 = __shfl(nw, i + 1, 64);
            const int   i2 = __shfl(idx, i + 2, 64); const float w2 = __shfl(nw, i + 2, 64);
            const int   i3 = __shfl(idx, i + 3, 64); const float w3 = __shfl(nw, i + 3, 64);
            const uint2 r0 = *(const uint2*)&h[(size_t)i0 * HID_C + f0];
            const uint2 r1 = *(const uint2*)&h[(size_t)i1 * HID_C + f0];
            const uint2 r2 = *(const uint2*)&h[(size_t)i2 * HID_C + f0];
            const uint2 r3 = *(const uint2*)&h[(size_t)i3 * HID_C + f0];
            fma4(acc, r0, w0); fma4(acc, r1, w1); fma4(acc, r2, w2); fma4(acc, r3, w3);
        }
        for (; i < cnt; ++i) {
            const int   ii = __shfl(idx, i, 64);
            const float w  = __shfl(nw,  i, 64);
            const uint2 r  = *(const uint2*)&h[(size_t)ii * HID_C + f0];
            fma4(acc, r, w);
        }
    }

    const float4 bv = *(const float4*)&b1[f0];
    const float v0 = fmaxf(acc[0] + bv.x, 0.f);
    const float v1 = fmaxf(acc[1] + bv.y, 0.f);
    const float v2 = fmaxf(acc[2] + bv.z, 0.f);
    const float v3 = fmaxf(acc[3] + bv.w, 0.f);
    const float4 wa = *(const float4*)&W2[f0 * 2];       // W2[f0][0..1], W2[f0+1][0..1]
    const float4 wb = *(const float4*)&W2[f0 * 2 + 4];   // W2[f0+2][0..1], W2[f0+3][0..1]
    float c0 = v0 * wa.x + v1 * wa.z + v2 * wb.x + v3 * wb.z;
    float c1 = v0 * wa.y + v1 * wa.w + v2 * wb.y + v3 * wb.w;
    #pragma unroll
    for (int o = 32; o > 0; o >>= 1) {
        c0 += __shfl_down(c0, o, 64);
        c1 += __shfl_down(c1, o, 64);
    }
    if (lane == 0) {
        h2[node * 2 + 0] = c0;
        h2[node * 2 + 1] = c1;
    }
}

// ---------------- aggregation-2 (+b2), 4-way ILP ----------------

__global__ void agg2_kernel(const float* __restrict__ h2,
                            const int* __restrict__ offs,
                            const int* __restrict__ csr_src,
                            const float* __restrict__ csr_norm,
                            const float* __restrict__ b2,
                            float* __restrict__ out, int n_nodes) {
    int n = blockIdx.x * blockDim.x + threadIdx.x;
    if (n >= n_nodes) return;
    const int s = offs[n], e = offs[n + 1];
    float a0 = b2[0], a1 = b2[1];
    int i = s;
    for (; i + 4 <= e; i += 4) {
        const int   i0 = csr_src[i],     i1 = csr_src[i + 1];
        const int   i2 = csr_src[i + 2], i3 = csr_src[i + 3];
        const float w0 = csr_norm[i],     w1 = csr_norm[i + 1];
        const float w2 = csr_norm[i + 2], w3 = csr_norm[i + 3];
        const float2 p0 = *(const float2*)&h2[i0 * 2];
        const float2 p1 = *(const float2*)&h2[i1 * 2];
        const float2 p2 = *(const float2*)&h2[i2 * 2];
        const float2 p3 = *(const float2*)&h2[i3 * 2];
        a0 += p0.x * w0 + p1.x * w1 + p2.x * w2 + p3.x * w3;
        a1 += p0.y * w0 + p1.y * w1 + p2.y * w2 + p3.y * w3;
    }
    for (; i < e; ++i) {
        const int   ii = csr_src[i];
        const float w  = csr_norm[i];
        const float2 p = *(const float2*)&h2[ii * 2];
        a0 += p.x * w;
        a1 += p.y * w;
    }
    out[n * 2 + 0] = a0;
    out[n * 2 + 1] = a1;
}

// ---------------- host ----------------

static inline size_t align_up(size_t x) { return (x + 255) & ~(size_t)255; }

extern "C" void kernel_launch(void* const* d_in, const int* in_sizes, int n_in,
                              void* d_out, int out_size, void* d_ws, size_t ws_size,
                              hipStream_t stream) {
    const float* x   = (const float*)d_in[0];
    const int*   ei  = (const int*)d_in[1];
    const float* W1  = (const float*)d_in[2];
    const float* b1  = (const float*)d_in[3];
    const float* W2  = (const float*)d_in[4];
    const float* b2  = (const float*)d_in[5];
    float* out = (float*)d_out;

    const int* e_src = ei;
    const int* e_dst = ei + N_EDGES;

    char* ws = (char*)d_ws;
    int*   counts   = (int*)ws;             ws += align_up((size_t)N_NODES * 4);
    int*   incl     = (int*)ws;             ws += align_up((size_t)N_NODES * 4);
    int*   bsum     = (int*)ws;             ws += align_up(256 * 4);
    int*   bpre     = (int*)ws;             ws += align_up(256 * 4);
    int*   offs     = (int*)ws;             ws += align_up((size_t)(N_NODES + 1) * 4);
    int*   cursor   = (int*)ws;             ws += align_up((size_t)N_NODES * 4);
    float* dinv     = (float*)ws;           ws += align_up((size_t)N_NODES * 4);
    int*   csr_src  = (int*)ws;             ws += align_up((size_t)TOT_E * 4);
    float* csr_norm = (float*)ws;           ws += align_up((size_t)TOT_E * 4);
    unsigned short* Wt = (unsigned short*)ws; ws += align_up((size_t)HID_C * IN_C * 2);
    unsigned short* h  = (unsigned short*)ws; ws += align_up((size_t)N_NODES * HID_C * 2);
    float* h2       = (float*)ws;           ws += align_up((size_t)N_NODES * 2 * 4);

    const int nb_n = (N_NODES + 255) / 256;   // 196
    const int nb_e = (N_EDGES + 255) / 256;
    const int nb_t = (TOT_E + 255) / 256;

    init_counts_kernel<<<nb_n, 256, 0, stream>>>(counts, N_NODES);
    count_kernel<<<nb_e, 256, 0, stream>>>(e_dst, counts, N_EDGES);
    dinv_kernel<<<nb_n, 256, 0, stream>>>(counts, dinv, N_NODES);
    scan1_kernel<<<nb_n, 256, 0, stream>>>(counts, incl, bsum, N_NODES);
    scan2_kernel<<<1, 256, 0, stream>>>(bsum, bpre, nb_n);
    scan3_kernel<<<nb_n, 256, 0, stream>>>(incl, counts, bpre, offs, cursor, N_NODES);
    transw_kernel<<<HID_C, 256, 0, stream>>>(W1, Wt);
    fill_kernel<<<nb_t, 256, 0, stream>>>(e_src, e_dst, dinv, cursor,
                                          csr_src, csr_norm, N_EDGES, N_NODES);

    gemm_kernel<<<(N_NODES + 63) / 64, 256, 0, stream>>>(x, Wt, h, N_NODES);

    agg1_kernel<<<N_NODES / 4, 256, 0, stream>>>(h, offs, csr_src, csr_norm, b1, W2, h2);
    agg2_kernel<<<nb_n, 256, 0, stream>>>(h2, offs, csr_src, csr_norm, b2, out, N_NODES);
}